// Round 4
// baseline (257.922 us; speedup 1.0000x reference)
//
#include <hip/hip_runtime.h>

// TransformerDecoderLayer: B=4,S=2048,D=512,H=8,DK=64,DFF=2048, fp32 in/out.
// bf16 MFMA GEMMs (global_load_lds + XOR chunk swizzle, TN=64 variant for N=512) +
// swapped-QK^T flash attention (32q/wave, gl_lds dbuf 1-barrier/tile, in-register
// P via cvt_pk + permlane16/32_swap, mask bitmap, defer-max) + fp32 LN.

typedef __bf16 bf16x8 __attribute__((ext_vector_type(8)));
typedef float f32x4 __attribute__((ext_vector_type(4)));
typedef unsigned short us4 __attribute__((ext_vector_type(4)));
typedef unsigned u32x4 __attribute__((ext_vector_type(4)));

__device__ __forceinline__ unsigned short f2bf(float f){
  unsigned u = __builtin_bit_cast(unsigned, f);
  u += 0x7fffu + ((u >> 16) & 1u);   // RNE
  return (unsigned short)(u >> 16);
}

__device__ __forceinline__ unsigned cvt_pk_bf16(float lo, float hi){
  unsigned r;
  asm("v_cvt_pk_bf16_f32 %0, %1, %2" : "=v"(r) : "v"(lo), "v"(hi));
  return r;
}
// dual-result lane swaps (gfx950): both operands updated in place
__device__ __forceinline__ void plswap32(unsigned &a, unsigned &b){
  asm volatile("v_permlane32_swap_b32 %0, %1" : "+v"(a), "+v"(b));
}
__device__ __forceinline__ void plswap16(unsigned &a, unsigned &b){
  asm volatile("v_permlane16_swap_b32 %0, %1" : "+v"(a), "+v"(b));
}

typedef const __attribute__((address_space(1))) void* gas_t;
typedef __attribute__((address_space(3))) void* las_t;
__device__ __forceinline__ void gl_lds16(const void* g, void* l){
  __builtin_amdgcn_global_load_lds((gas_t)g, (las_t)l, 16, 0, 0);
}

// ---------- f32 -> bf16 convert ----------
__global__ void k_f2b(const float* __restrict__ in, unsigned short* __restrict__ out, int n4){
  int i = blockIdx.x * 256 + threadIdx.x;
  if (i < n4){
    float4 v = reinterpret_cast<const float4*>(in)[i];
    us4 o = { f2bf(v.x), f2bf(v.y), f2bf(v.z), f2bf(v.w) };
    reinterpret_cast<us4*>(out)[i] = o;
  }
}

// ---------- weight transpose+convert: in[K][N] f32 -> out[N][K] bf16 ----------
__global__ void k_wtrans(const float* __restrict__ in, unsigned short* __restrict__ out, int K, int N){
  __shared__ float t[32][33];
  int k0 = blockIdx.x*32, n0 = blockIdx.y*32;
  int tx = threadIdx.x & 31, ty = threadIdx.x >> 5;
  #pragma unroll
  for (int r = 0; r < 4; ++r)
    t[ty + 8*r][tx] = in[(size_t)(k0 + ty + 8*r)*N + n0 + tx];
  __syncthreads();
  #pragma unroll
  for (int r = 0; r < 4; ++r)
    out[(size_t)(n0 + ty + 8*r)*K + k0 + tx] = f2bf(t[tx][ty + 8*r]);
}

// qkv weights [H,512,64] (x3) -> Wt_qkv[1536][512]
__global__ void k_wtrans_qkv(const float* __restrict__ qw, const float* __restrict__ kw,
                             const float* __restrict__ vw, unsigned short* __restrict__ out){
  __shared__ float t[32][33];
  int z = blockIdx.z, sel = z >> 3, h = z & 7;
  const float* in = (sel==0 ? qw : (sel==1 ? kw : vw)) + (size_t)h*512*64;
  unsigned short* o = out + ((size_t)(sel*512 + h*64)) * 512;
  int k0 = blockIdx.x*32, n0 = blockIdx.y*32;
  int tx = threadIdx.x & 31, ty = threadIdx.x >> 5;
  #pragma unroll
  for (int r = 0; r < 4; ++r)
    t[ty + 8*r][tx] = in[(size_t)(k0 + ty + 8*r)*64 + n0 + tx];
  __syncthreads();
  #pragma unroll
  for (int r = 0; r < 4; ++r)
    o[(size_t)(n0 + ty + 8*r)*512 + k0 + tx] = f2bf(t[tx][ty + 8*r]);
}

__global__ void k_bqkv(const float* __restrict__ qb, const float* __restrict__ kb,
                       const float* __restrict__ vb, float* __restrict__ out){
  int n = blockIdx.x*256 + threadIdx.x;
  if (n < 1536){ int sel = n >> 9, r = n & 511;
    out[n] = (sel==0 ? qb : (sel==1 ? kb : vb))[r]; }
}

// ---------- mask tile bitmap ----------
__global__ __launch_bounds__(256) void k_maskbits(const int* __restrict__ mask, unsigned short* __restrict__ out){
  const int tid = threadIdx.x;
  const int bq = blockIdx.x;            // b*32 + qt64
  const int half = blockIdx.y;
  const int b = bq >> 5, qt = bq & 31;
  const int* base = mask + (size_t)b*2048*2048 + (size_t)(qt*64 + (tid>>4)*4)*2048 + (tid&15)*4;
  unsigned bits = 0;
  for (int i = 0; i < 16; ++i){
    const int* p = base + (half*16 + i)*64;
    int ok = 1;
    #pragma unroll
    for (int r = 0; r < 4; ++r){
      int4 v = *reinterpret_cast<const int4*>(p + (size_t)r*2048);
      ok &= (v.x!=0)&(v.y!=0)&(v.z!=0)&(v.w!=0);
    }
    bits |= (unsigned)ok << i;
  }
  #pragma unroll
  for (int o = 1; o < 64; o <<= 1) bits &= __shfl_xor(bits, o);
  __shared__ unsigned red[4];
  if ((tid & 63) == 0) red[tid >> 6] = bits;
  __syncthreads();
  if (tid == 0) out[bq*2 + half] = (unsigned short)(red[0]&red[1]&red[2]&red[3]);
}

// ---------- GEMM: C[M,N] = A[M,K](bf16) * Bt[N,K]^T (bf16) + bias, fused epilogues ----------
// TN = 128 or 64 (64 for the N=512 shapes -> 2 blocks/CU instead of 1)
template<int MODE, int TN>
__global__ __launch_bounds__(256, 3) void k_gemm(
    const unsigned short* __restrict__ A, const unsigned short* __restrict__ Bt,
    const float* __restrict__ bias, const float* __restrict__ resid,
    unsigned short* __restrict__ ob0, unsigned short* __restrict__ ob1, unsigned short* __restrict__ ob2,
    float* __restrict__ of, int M, int N, int K)
{
  constexpr int NI = TN / 32;            // acc cols per wave
  __shared__ unsigned short As[128*32];
  __shared__ unsigned short Bs[TN*32];
  const int tid = threadIdx.x, lane = tid & 63, wid = tid >> 6;
  const int g = lane >> 4, lr = lane & 15;
  const int rowBase = blockIdx.x * 128, colBase = blockIdx.y * TN;
  const int wr = (wid >> 1) * 64, wc = (wid & 1) * (TN/2);
  const int srow = wid*32 + (lane >> 2);
  const int gcol = ((lane & 3) ^ ((lane >> 3) & 3)) * 8;   // shorts, src chunk XOR (row>>1)&3
  const int rchunk = (g ^ ((lr >> 1) & 3)) * 8;
  unsigned short* lA = &As[wid*1024];
  const unsigned short* pA = A + (size_t)(rowBase + srow)*K + gcol;
  const int srowB = (TN == 128) ? srow : (wid*16 + (lane >> 2));
  unsigned short* lB = (TN == 128) ? &Bs[wid*1024] : &Bs[wid*512];
  const unsigned short* pB = Bt + (size_t)(colBase + srowB)*K + gcol;
  f32x4 acc[4][NI] = {};
  for (int k0 = 0; k0 < K; k0 += 32){
    __syncthreads();
    gl_lds16(pA + k0, lA);
    gl_lds16(pA + (size_t)16*K + k0, lA + 512);
    if constexpr (TN == 128){
      gl_lds16(pB + k0, lB);
      gl_lds16(pB + (size_t)16*K + k0, lB + 512);
    } else {
      gl_lds16(pB + k0, lB);
    }
    __syncthreads();
    bf16x8 af[4], bfr[NI];
    #pragma unroll
    for (int mi = 0; mi < 4; ++mi) af[mi]  = *reinterpret_cast<const bf16x8*>(&As[(wr + mi*16 + lr)*32 + rchunk]);
    #pragma unroll
    for (int ni = 0; ni < NI; ++ni) bfr[ni] = *reinterpret_cast<const bf16x8*>(&Bs[(wc + ni*16 + lr)*32 + rchunk]);
    #pragma unroll
    for (int mi = 0; mi < 4; ++mi)
      #pragma unroll
      for (int ni = 0; ni < NI; ++ni)
        acc[mi][ni] = __builtin_amdgcn_mfma_f32_16x16x32_bf16(af[mi], bfr[ni], acc[mi][ni], 0, 0, 0);
  }
  float bv[NI];
  #pragma unroll
  for (int ni = 0; ni < NI; ++ni) bv[ni] = bias[colBase + wc + ni*16 + lr];
  #pragma unroll
  for (int mi = 0; mi < 4; ++mi){
    #pragma unroll
    for (int ni = 0; ni < NI; ++ni){
      #pragma unroll
      for (int j = 0; j < 4; ++j){
        int m = rowBase + wr + mi*16 + g*4 + j;
        int n = colBase + wc + ni*16 + lr;
        float v = acc[mi][ni][j] + bv[ni];
        if constexpr (MODE == 0){
          int b = m >> 11, s = m & 2047;
          int sel = n >> 9, rr = n & 511, h = rr >> 6, e = rr & 63;
          size_t bh = (size_t)(b*8 + h);
          if (sel == 0)      ob0[(bh*2048 + s)*64 + e] = f2bf(v);
          else if (sel == 1) ob1[(bh*2048 + s)*64 + e] = f2bf(v);
          else               ob2[(bh*64 + e)*2048 + s] = f2bf(v);   // V transposed
        } else if constexpr (MODE == 1 || MODE == 3){
          of[(size_t)m*N + n] = v + resid[(size_t)m*N + n];
        } else {
          ob0[(size_t)m*N + n] = f2bf(v > 0.f ? v : 0.f);
        }
      }
    }
  }
}

// ---------- flash attention, swapped QK^T, 32 q/wave, in-register P ----------
// grid (16, 32); block 256 = 4 waves; wave owns 32 q (2 groups of 16).
// K/V double-buffered in LDS via global_load_lds (pre-swizzled source chunk),
// one barrier per tile; P exchanged via cvt_pk + permlane32/16_swap (no P LDS).
__global__ __launch_bounds__(256) void k_attn(
    const unsigned short* __restrict__ Qb, const unsigned short* __restrict__ Kb,
    const unsigned short* __restrict__ Vt, const int* __restrict__ mask,
    const unsigned* __restrict__ mbits_p, unsigned short* __restrict__ ctx)
{
  __shared__ unsigned short Ks[2][4096];   // [64 rows][8 chunks of 8 shorts], chunk-XOR layout
  __shared__ unsigned short Vs[2][4096];
  const int tid = threadIdx.x, lane = tid & 63, wid = tid >> 6;
  const int g = lane >> 4, lr = lane & 15;
  const int qt = blockIdx.x, bh = blockIdx.y;
  const int b = bh >> 3, h = bh & 7;
  const int qw = qt * 128 + wid * 32;
  const unsigned mbits = mbits_p[b*64 + qt*2] & mbits_p[b*64 + qt*2 + 1];
  const size_t mbase = (size_t)b * 2048 * 2048;
  const float SC = 0.18033688f;   // log2(e)/sqrt(64)

  bf16x8 b_q[2][2];   // [qg][ks]: Q as B-operand, col q = lr, k(e) = ks*32 + 8g + j
  #pragma unroll
  for (int qg = 0; qg < 2; ++qg){
    const unsigned short* qp = Qb + ((size_t)bh*2048 + qw + qg*16 + lr)*64;
    b_q[qg][0] = *reinterpret_cast<const bf16x8*>(qp + g*8);
    b_q[qg][1] = *reinterpret_cast<const bf16x8*>(qp + 32 + g*8);
  }
  f32x4 acc[2][4] = {};    // [qg][ne] ctx^T frags: row e = ne*16+4g+j, col q = lr
  float m_run[2] = {-3.0e38f, -3.0e38f}, l_run[2] = {0.f, 0.f};

  // staging: each wave covers rows [wid*16, wid*16+16) via 2 gl_lds per matrix.
  // lane covers LDS slot (row8 = l>>3, chunk = l&7); source chunk = (l&7)^(row&7).
  const int srow8 = lane >> 3;
  const int schunk = (lane & 7) ^ (srow8 & 7);
  const unsigned short* kgb = Kb + (size_t)bh*2048*64 + ((size_t)(wid*16) + srow8)*64 + schunk*8;
  const unsigned short* vgb = Vt + (size_t)bh*64*2048 + ((size_t)(wid*16) + srow8)*2048 + schunk*8;

  #define STAGE(buf, t) do { \
    gl_lds16(kgb + (size_t)(t)*4096,        &Ks[buf][(wid*16)*64]);   \
    gl_lds16(kgb + (size_t)(t)*4096 + 512,  &Ks[buf][(wid*16+8)*64]); \
    gl_lds16(vgb + (size_t)(t)*64,          &Vs[buf][(wid*16)*64]);   \
    gl_lds16(vgb + (size_t)(t)*64 + 8*2048, &Vs[buf][(wid*16+8)*64]); \
  } while(0)

  STAGE(0, 0);
  __syncthreads();
  int cur = 0;

  for (int kt = 0; kt < 32; ++kt){
    if (kt < 31) STAGE(cur^1, kt+1);
    const unsigned short* Kc = Ks[cur];
    const unsigned short* Vc = Vs[cur];
    // QK^T (swapped): A = K rows (k = mk*16+4g+j), B = Q (col q = lr)
    f32x4 st[2][4] = {};
    __builtin_amdgcn_s_setprio(1);
    #pragma unroll
    for (int mk = 0; mk < 4; ++mk){
      #pragma unroll
      for (int ks = 0; ks < 2; ++ks){
        bf16x8 kf = *reinterpret_cast<const bf16x8*>(
            &Kc[(mk*16 + lr)*64 + (((ks*4 + g) ^ (lr & 7)))*8]);
        st[0][mk] = __builtin_amdgcn_mfma_f32_16x16x32_bf16(kf, b_q[0][ks], st[0][mk], 0,0,0);
        st[1][mk] = __builtin_amdgcn_mfma_f32_16x16x32_bf16(kf, b_q[1][ks], st[1][mk], 0,0,0);
      }
    }
    __builtin_amdgcn_s_setprio(0);
    if (!((mbits >> kt) & 1)){
      const int kk0 = kt * 64;
      #pragma unroll
      for (int qg = 0; qg < 2; ++qg)
        #pragma unroll
        for (int mk = 0; mk < 4; ++mk)
          #pragma unroll
          for (int j = 0; j < 4; ++j){
            int kg = kk0 + mk*16 + g*4 + j;
            if (mask[mbase + (size_t)(qw + qg*16 + lr)*2048 + kg] == 0) st[qg][mk][j] = -3.0e30f;
          }
    }
    // online softmax (log2 domain)
    float tm[2];
    #pragma unroll
    for (int qg = 0; qg < 2; ++qg){
      float a0 = fmaxf(fmaxf(st[qg][0][0], st[qg][0][1]), fmaxf(st[qg][0][2], st[qg][0][3]));
      float a1 = fmaxf(fmaxf(st[qg][1][0], st[qg][1][1]), fmaxf(st[qg][1][2], st[qg][1][3]));
      float a2 = fmaxf(fmaxf(st[qg][2][0], st[qg][2][1]), fmaxf(st[qg][2][2], st[qg][2][3]));
      float a3 = fmaxf(fmaxf(st[qg][3][0], st[qg][3][1]), fmaxf(st[qg][3][2], st[qg][3][3]));
      float t = fmaxf(fmaxf(a0, a1), fmaxf(a2, a3));
      t = fmaxf(t, __shfl_xor(t, 16));
      t = fmaxf(t, __shfl_xor(t, 32));
      tm[qg] = t * SC;
    }
    bool ok = (tm[0] <= m_run[0] + 8.f) & (tm[1] <= m_run[1] + 8.f);
    if (!__all(ok)){
      #pragma unroll
      for (int qg = 0; qg < 2; ++qg){
        float mnew = fmaxf(m_run[qg], tm[qg]);
        float alpha = exp2f(m_run[qg] - mnew);
        l_run[qg] *= alpha;
        #pragma unroll
        for (int ne = 0; ne < 4; ++ne)
          #pragma unroll
          for (int j = 0; j < 4; ++j) acc[qg][ne][j] *= alpha;
        m_run[qg] = mnew;
      }
    }
    // exp2 -> packed bf16 words -> permlane exchange -> PV B-frags (no LDS)
    bf16x8 pw[2][2];   // [qg][ks]
    #pragma unroll
    for (int qg = 0; qg < 2; ++qg){
      float mr = m_run[qg];
      float psA = 0.f, psB = 0.f;
      unsigned wrd[4][2];
      #pragma unroll
      for (int mk = 0; mk < 4; ++mk){
        float p0 = exp2f(__builtin_fmaf(st[qg][mk][0], SC, -mr));
        float p1 = exp2f(__builtin_fmaf(st[qg][mk][1], SC, -mr));
        float p2 = exp2f(__builtin_fmaf(st[qg][mk][2], SC, -mr));
        float p3 = exp2f(__builtin_fmaf(st[qg][mk][3], SC, -mr));
        psA += p0 + p2; psB += p1 + p3;
        wrd[mk][0] = cvt_pk_bf16(p0, p1);
        wrd[mk][1] = cvt_pk_bf16(p2, p3);
      }
      float ps = psA + psB;
      ps += __shfl_xor(ps, 16);
      ps += __shfl_xor(ps, 32);
      l_run[qg] += ps;
      #pragma unroll
      for (int ks = 0; ks < 2; ++ks){
        unsigned a0 = wrd[2*ks][0], b0 = wrd[2*ks+1][0];
        unsigned a1 = wrd[2*ks][1], b1 = wrd[2*ks+1][1];
        plswap32(a0, b0); plswap16(a0, b0);   // a0=word0 (k 0,1 of 8), b0=word2 (k 4,5)
        plswap32(a1, b1); plswap16(a1, b1);   // a1=word1 (k 2,3),      b1=word3 (k 6,7)
        u32x4 pk = { a0, a1, b0, b1 };
        pw[qg][ks] = __builtin_bit_cast(bf16x8, pk);
      }
    }
    // PV: ctx^T += Vt * P^T ; A = Vt rows e, B = pw (col q = lr)
    #pragma unroll
    for (int ks = 0; ks < 2; ++ks){
      __builtin_amdgcn_s_setprio(1);
      #pragma unroll
      for (int ne = 0; ne < 4; ++ne){
        bf16x8 vf = *reinterpret_cast<const bf16x8*>(
            &Vc[(ne*16 + lr)*64 + (((ks*4 + g) ^ (lr & 7)))*8]);
        acc[0][ne] = __builtin_amdgcn_mfma_f32_16x16x32_bf16(vf, pw[0][ks], acc[0][ne], 0,0,0);
        acc[1][ne] = __builtin_amdgcn_mfma_f32_16x16x32_bf16(vf, pw[1][ks], acc[1][ne], 0,0,0);
      }
      __builtin_amdgcn_s_setprio(0);
    }
    if (kt < 31){
      __syncthreads();   // drains staged DMA (vmcnt) + orders buffer reuse
      cur ^= 1;
    }
  }
  #undef STAGE
  #pragma unroll
  for (int qg = 0; qg < 2; ++qg){
    float inv = 1.f / l_run[qg];
    int q = qw + qg*16 + lr;
    #pragma unroll
    for (int ne = 0; ne < 4; ++ne)
      #pragma unroll
      for (int j = 0; j < 4; ++j){
        int e = ne*16 + g*4 + j;
        ctx[((size_t)b*2048 + q)*512 + h*64 + e] = f2bf(acc[qg][ne][j] * inv);
      }
  }
}

// ---------- LayerNorm: wave per row of 512 ----------
__global__ __launch_bounds__(256) void k_ln(
    const float* __restrict__ in, const float* __restrict__ gma, const float* __restrict__ bta,
    float* __restrict__ of, unsigned short* __restrict__ ob)
{
  const int lane = threadIdx.x & 63, wid = threadIdx.x >> 6;
  const size_t row = (size_t)blockIdx.x * 4 + wid;
  const float* x = in + row * 512;
  const int e0 = lane * 8;
  float xv[8];
  *reinterpret_cast<float4*>(&xv[0]) = *reinterpret_cast<const float4*>(x + e0);
  *reinterpret_cast<float4*>(&xv[4]) = *reinterpret_cast<const float4*>(x + e0 + 4);
  float s = 0.f, ss = 0.f;
  #pragma unroll
  for (int i = 0; i < 8; ++i){ s += xv[i]; ss += xv[i]*xv[i]; }
  #pragma unroll
  for (int o = 1; o < 64; o <<= 1){ s += __shfl_xor(s, o); ss += __shfl_xor(ss, o); }
  float mu = s * (1.f/512.f);
  float var = ss * (1.f/512.f) - mu*mu;
  float rs = rsqrtf(var + 1e-5f);
  float gv[8], bv[8], y[8];
  *reinterpret_cast<float4*>(&gv[0]) = *reinterpret_cast<const float4*>(gma + e0);
  *reinterpret_cast<float4*>(&gv[4]) = *reinterpret_cast<const float4*>(gma + e0 + 4);
  *reinterpret_cast<float4*>(&bv[0]) = *reinterpret_cast<const float4*>(bta + e0);
  *reinterpret_cast<float4*>(&bv[4]) = *reinterpret_cast<const float4*>(bta + e0 + 4);
  #pragma unroll
  for (int i = 0; i < 8; ++i) y[i] = (xv[i]-mu)*rs*gv[i] + bv[i];
  *reinterpret_cast<float4*>(of + row*512 + e0)     = *reinterpret_cast<float4*>(&y[0]);
  *reinterpret_cast<float4*>(of + row*512 + e0 + 4) = *reinterpret_cast<float4*>(&y[4]);
  if (ob){
    us4 o0 = { f2bf(y[0]), f2bf(y[1]), f2bf(y[2]), f2bf(y[3]) };
    us4 o1 = { f2bf(y[4]), f2bf(y[5]), f2bf(y[6]), f2bf(y[7]) };
    *reinterpret_cast<us4*>(ob + row*512 + e0)     = o0;
    *reinterpret_cast<us4*>(ob + row*512 + e0 + 4) = o1;
  }
}

extern "C" void kernel_launch(void* const* d_in, const int* in_sizes, int n_in,
                              void* d_out, int out_size, void* d_ws, size_t ws_size,
                              hipStream_t stream)
{
  const float* src  = (const float*)d_in[0];
  const int*   mask = (const int*)d_in[1];
  const float* q_w  = (const float*)d_in[2];
  const float* q_b  = (const float*)d_in[3];
  const float* k_w  = (const float*)d_in[4];
  const float* k_b  = (const float*)d_in[5];
  const float* v_w  = (const float*)d_in[6];
  const float* v_b  = (const float*)d_in[7];
  const float* o_w  = (const float*)d_in[8];
  const float* o_b  = (const float*)d_in[9];
  const float* ln1g = (const float*)d_in[10];
  const float* ln1b = (const float*)d_in[11];
  const float* w1   = (const float*)d_in[12];
  const float* b1   = (const float*)d_in[13];
  const float* w2   = (const float*)d_in[14];
  const float* b2   = (const float*)d_in[15];
  const float* ln2g = (const float*)d_in[16];
  const float* ln2b = (const float*)d_in[17];

  char* ws = (char*)d_ws;
  if (ws_size < 81795072) return;
  unsigned short* x_bf  = (unsigned short*)(ws + 0);          // 8.4MB (reused as LN1 bf16 out)
  unsigned short* wtqkv = (unsigned short*)(ws + 8388608);
  float*          bqkv  = (float*)(ws + 9961472);
  unsigned short* wto   = (unsigned short*)(ws + 9967616);
  unsigned short* wt1   = (unsigned short*)(ws + 10491904);
  unsigned short* wt2   = (unsigned short*)(ws + 12589056);
  unsigned short* Qb    = (unsigned short*)(ws + 14686208);
  unsigned short* Kb    = (unsigned short*)(ws + 23074816);
  unsigned short* Vt    = (unsigned short*)(ws + 31463424);
  unsigned short* ctx   = (unsigned short*)(ws + 39852032);
  unsigned short* ffb   = (unsigned short*)(ws + 14686208);   // overlays Q/K/Vt/ctx (dead by FF1)
  float* res = (float*)(ws + 48240640);                        // res1 then res2
  float* xf  = (float*)(ws + 65017856);
  unsigned short* mb16 = (unsigned short*)(ws + 48240640);     // bitmap in res head (dead by gemm<1>)
  const unsigned* mb32 = (const unsigned*)(ws + 48240640);
  float* outf = (float*)d_out;

  k_maskbits<<<dim3(128,2), 256, 0, stream>>>(mask, mb16);
  k_f2b<<<4096, 256, 0, stream>>>(src, x_bf, 1048576);
  k_wtrans_qkv<<<dim3(16,2,24), 256, 0, stream>>>(q_w, k_w, v_w, wtqkv);
  k_bqkv<<<6, 256, 0, stream>>>(q_b, k_b, v_b, bqkv);
  k_wtrans<<<dim3(16,16), 256, 0, stream>>>(o_w, wto, 512, 512);
  k_wtrans<<<dim3(16,64), 256, 0, stream>>>(w1, wt1, 512, 2048);
  k_wtrans<<<dim3(64,16), 256, 0, stream>>>(w2, wt2, 2048, 512);

  k_gemm<0,128><<<dim3(64,12), 256, 0, stream>>>(x_bf, wtqkv, bqkv, nullptr,
                                                 Qb, Kb, Vt, nullptr, 8192, 1536, 512);
  k_attn<<<dim3(16,32), 256, 0, stream>>>(Qb, Kb, Vt, mask, mb32, ctx);
  k_gemm<1,64><<<dim3(64,8), 256, 0, stream>>>(ctx, wto, o_b, src,
                                               nullptr, nullptr, nullptr, res, 8192, 512, 512);
  k_ln<<<2048, 256, 0, stream>>>(res, ln1g, ln1b, xf, x_bf);
  k_gemm<2,128><<<dim3(64,16), 256, 0, stream>>>(x_bf, wt1, b1, nullptr,
                                                 ffb, nullptr, nullptr, nullptr, 8192, 2048, 512);
  k_gemm<3,64><<<dim3(64,8), 256, 0, stream>>>(ffb, wt2, b2, xf,
                                               nullptr, nullptr, nullptr, res, 8192, 512, 2048);
  k_ln<<<2048, 256, 0, stream>>>(res, ln2g, ln2b, outf, nullptr);
}